// Round 1
// baseline (141.741 us; speedup 1.0000x reference)
//
#include <hip/hip_runtime.h>

#define CC 8
#define HH 256
#define WW 512
#define KK 9
#define XF 268   // LDS floats per channel row: window [seg*256-4, seg*256+260), 264 used

__global__ __launch_bounds__(256) void dynfilter_kernel(
    const float* __restrict__ x,
    const float* __restrict__ filt,
    const float* __restrict__ fbias,
    float* __restrict__ out)
{
    __shared__ __align__(16) float xs[2][CC][XF];

    const int tid = threadIdx.x;
    const int bid = blockIdx.x;          // 1024 = seg(2) * h(256) * n(2)
    const int seg = bid & 1;
    const int h   = (bid >> 1) & 255;
    const int n   = bid >> 9;

    const int pxg = tid & 127;           // 128 pixel-groups of 2 px
    const int cg  = tid >> 7;            // channel-group: 0 -> ch0-3, 1 -> ch4-7
    const int w0  = seg * 256 + (pxg << 1);

    const int lane32  = tid & 31;        // staging: 8 channels x 32 lanes
    const int cstage  = tid >> 5;
    const int wstage0 = seg * 256 - 4;
    const float* xcrow = x + ((size_t)(n * CC + cstage)) * ((size_t)HH * WW) + wstage0;

    const size_t HW = (size_t)HH * WW;
    const float* fptr = filt + ((size_t)(n * 81) * HH + h) * WW + w0;

    float acc[4][2];
    {
        const float2 fb2 = *(const float2*)(fbias + ((size_t)(n * HH + h)) * WW + w0);
        acc[0][0] = fb2.x; acc[0][1] = fb2.y;
        acc[1][0] = fb2.x; acc[1][1] = fb2.y;
        acc[2][0] = fb2.x; acc[2][1] = fb2.y;
        acc[3][0] = fb2.x; acc[3][1] = fb2.y;
    }

    // ---- prologue: stage row h-4 into buf 0, prefetch tap-row 0 into regs ----
    {
        const int hh = h - 4;
        const bool rowok = (hh >= 0);
        const float* src = xcrow + (size_t)hh * WW;
        float4 s0 = make_float4(0.f,0.f,0.f,0.f), s1 = s0, s2 = s0;
        int w;
        w = wstage0 + (lane32 << 2);
        if (rowok && (unsigned)w < (unsigned)WW) s0 = *(const float4*)(src + (lane32 << 2));
        w = wstage0 + ((lane32 + 32) << 2);
        if (rowok && (unsigned)w < (unsigned)WW) s1 = *(const float4*)(src + ((lane32 + 32) << 2));
        w = wstage0 + ((lane32 + 64) << 2);
        if (lane32 < 2 && rowok && (unsigned)w < (unsigned)WW) s2 = *(const float4*)(src + ((lane32 + 64) << 2));
        *(float4*)&xs[0][cstage][lane32 << 2] = s0;
        *(float4*)&xs[0][cstage][(lane32 + 32) << 2] = s1;
        if (lane32 < 2) *(float4*)&xs[0][cstage][(lane32 + 64) << 2] = s2;
    }

    // filter taps for tap-row 0 (registers; double-buffered across the loop)
    float2 fa0, fa1, fa2, fa3, fa4, fa5, fa6, fa7, fa8;
    fa0 = *(const float2*)(fptr + 0 * HW);
    fa1 = *(const float2*)(fptr + 1 * HW);
    fa2 = *(const float2*)(fptr + 2 * HW);
    fa3 = *(const float2*)(fptr + 3 * HW);
    fa4 = *(const float2*)(fptr + 4 * HW);
    fa5 = *(const float2*)(fptr + 5 * HW);
    fa6 = *(const float2*)(fptr + 6 * HW);
    fa7 = *(const float2*)(fptr + 7 * HW);
    fa8 = *(const float2*)(fptr + 8 * HW);

    __syncthreads();

    // ---- main loop over tap rows ----
    // CRITICAL: compiler auto-unrolls trip-count-9 loops, then hoists all 81
    // filter loads -> 256 VGPR + scratch spill. unroll(disable) is the fix.
    // Filter stream is software-pipelined one tap-row ahead (fa=cur, fb=next):
    // the vmcnt wait for the HBM-cold filter loads lands AFTER the 72-FMA
    // block (at the rotate) instead of before it.
    #pragma clang loop unroll(disable)
    for (int i = 0; i < KK; ++i) {
        const int buf = i & 1;

        // 1) issue next-row x staging loads (stay in flight during compute)
        float4 s0 = make_float4(0.f,0.f,0.f,0.f), s1 = s0, s2 = s0;
        if (i < KK - 1) {
            const int hh = h - 3 + i;
            const bool rowok = (unsigned)hh < (unsigned)HH;
            const float* src = xcrow + (size_t)hh * WW;
            int w;
            w = wstage0 + (lane32 << 2);
            if (rowok && (unsigned)w < (unsigned)WW) s0 = *(const float4*)(src + (lane32 << 2));
            w = wstage0 + ((lane32 + 32) << 2);
            if (rowok && (unsigned)w < (unsigned)WW) s1 = *(const float4*)(src + ((lane32 + 32) << 2));
            w = wstage0 + ((lane32 + 64) << 2);
            if (lane32 < 2 && rowok && (unsigned)w < (unsigned)WW) s2 = *(const float4*)(src + ((lane32 + 64) << 2));
        }

        // 2) prefetch NEXT tap-row's 9 taps (consumed next iteration)
        float2 fb0, fb1, fb2, fb3, fb4, fb5, fb6, fb7, fb8;
        if (i < KK - 1) {
            const float* fi = fptr + (size_t)(i + 1) * KK * HW;
            fb0 = *(const float2*)(fi + 0 * HW);
            fb1 = *(const float2*)(fi + 1 * HW);
            fb2 = *(const float2*)(fi + 2 * HW);
            fb3 = *(const float2*)(fi + 3 * HW);
            fb4 = *(const float2*)(fi + 4 * HW);
            fb5 = *(const float2*)(fi + 5 * HW);
            fb6 = *(const float2*)(fi + 6 * HW);
            fb7 = *(const float2*)(fi + 7 * HW);
            fb8 = *(const float2*)(fi + 8 * HW);
        }

        // 3) compute from current buffer with current taps (no vmem wait here)
        #pragma unroll
        for (int c = 0; c < 4; ++c) {
            const float* xp = &xs[buf][(cg << 2) + c][pxg << 1];
            float2 v0 = *(const float2*)(xp + 0);
            float2 v1 = *(const float2*)(xp + 2);
            float2 v2 = *(const float2*)(xp + 4);
            float2 v3 = *(const float2*)(xp + 6);
            float2 v4 = *(const float2*)(xp + 8);
            float a0 = acc[c][0], a1 = acc[c][1];
            a0 = fmaf(fa0.x, v0.x, a0);  a1 = fmaf(fa0.y, v0.y, a1);
            a0 = fmaf(fa1.x, v0.y, a0);  a1 = fmaf(fa1.y, v1.x, a1);
            a0 = fmaf(fa2.x, v1.x, a0);  a1 = fmaf(fa2.y, v1.y, a1);
            a0 = fmaf(fa3.x, v1.y, a0);  a1 = fmaf(fa3.y, v2.x, a1);
            a0 = fmaf(fa4.x, v2.x, a0);  a1 = fmaf(fa4.y, v2.y, a1);
            a0 = fmaf(fa5.x, v2.y, a0);  a1 = fmaf(fa5.y, v3.x, a1);
            a0 = fmaf(fa6.x, v3.x, a0);  a1 = fmaf(fa6.y, v3.y, a1);
            a0 = fmaf(fa7.x, v3.y, a0);  a1 = fmaf(fa7.y, v4.x, a1);
            a0 = fmaf(fa8.x, v4.x, a0);  a1 = fmaf(fa8.y, v4.y, a1);
            acc[c][0] = a0; acc[c][1] = a1;
        }

        // 4) store staged row into the other buffer; single barrier per iter
        if (i < KK - 1) {
            *(float4*)&xs[buf ^ 1][cstage][lane32 << 2] = s0;
            *(float4*)&xs[buf ^ 1][cstage][(lane32 + 32) << 2] = s1;
            if (lane32 < 2) *(float4*)&xs[buf ^ 1][cstage][(lane32 + 64) << 2] = s2;
        }

        // 5) rotate tap double-buffer (vmcnt wait for fb lands here, post-FMA)
        if (i < KK - 1) {
            fa0 = fb0; fa1 = fb1; fa2 = fb2; fa3 = fb3; fa4 = fb4;
            fa5 = fb5; fa6 = fb6; fa7 = fb7; fa8 = fb8;
        }
        __syncthreads();
    }

    #pragma unroll
    for (int c = 0; c < 4; ++c) {
        *(float2*)(out + ((size_t)(n * CC + (cg << 2) + c) * HH + h) * WW + w0) =
            make_float2(acc[c][0], acc[c][1]);
    }
}

extern "C" void kernel_launch(void* const* d_in, const int* in_sizes, int n_in,
                              void* d_out, int out_size, void* d_ws, size_t ws_size,
                              hipStream_t stream) {
    const float* x  = (const float*)d_in[0];
    const float* f  = (const float*)d_in[1];
    const float* fb = (const float*)d_in[2];
    float* o = (float*)d_out;
    hipLaunchKernelGGL(dynfilter_kernel, dim3(1024), dim3(256), 0, stream,
                       x, f, fb, o);
}

// Round 2
// 137.543 us; speedup vs baseline: 1.0305x; 1.0305x over previous
//
#include <hip/hip_runtime.h>

#define CC 8
#define HH 256
#define WW 512
#define KK 9
#define XF 272   // LDS floats per (wave,buf,ch) row: 264 used, padded to 16B multiple

__global__ __launch_bounds__(256, 4) void dynfilter_kernel(
    const float* __restrict__ x,
    const float* __restrict__ filt,
    const float* __restrict__ fbias,
    float* __restrict__ out)
{
    // Wave-private LDS double buffer: NO __syncthreads in this kernel.
    // R1 lesson: any barrier forces s_waitcnt vmcnt(0) for the whole block,
    // gang-draining the cold filter stream 9x per block. Each wave owns
    // channels {2w,2w+1} and stages them itself; same-wave ds_write->ds_read
    // ordering is covered by compiler-inserted lgkmcnt waits.
    __shared__ __align__(16) float xs[4][2][2][XF];

    const int tid  = threadIdx.x;
    const int wv   = tid >> 6;          // wave -> channels {2wv, 2wv+1}
    const int lane = tid & 63;

    const int bid = blockIdx.x;         // 1024 = seg(2) * h(256) * n(2)
    const int seg = bid & 1;
    const int h   = (bid >> 1) & 255;
    const int n   = bid >> 9;

    const int w0      = seg * 256 + (lane << 2);  // 4 px per lane
    const int wstage0 = seg * 256 - 4;

    const size_t HW = (size_t)HH * WW;
    const int c0 = wv << 1;

    const float* xr0  = x + (size_t)(n * CC + c0)     * HW + wstage0;
    const float* xr1  = x + (size_t)(n * CC + c0 + 1) * HW + wstage0;
    const float* fptr = filt + ((size_t)(n * 81) * HH + h) * WW + w0;

    float acc0[4], acc1[4];
    {
        const float4 b4 = *(const float4*)(fbias + ((size_t)(n * HH + h)) * WW + w0);
        acc0[0]=b4.x; acc0[1]=b4.y; acc0[2]=b4.z; acc0[3]=b4.w;
        acc1[0]=b4.x; acc1[1]=b4.y; acc1[2]=b4.z; acc1[3]=b4.w;
    }

    const int wlo = wstage0 + (lane << 2);         // main float4 start coord
    const int whi = wstage0 + 256 + (lane << 2);   // tail float4 (lanes 0,1)
    const bool lo_ok = (unsigned)wlo < (unsigned)WW;
    const bool hi_ok = (lane < 2) && ((unsigned)whi < (unsigned)WW);

    // ---- prologue: stage row h-4 into buf 0 (wave-private, no barrier) ----
    {
        const int hh = h - 4;
        const bool rowok = hh >= 0;
        const float* s0 = xr0 + (size_t)hh * WW;
        const float* s1 = xr1 + (size_t)hh * WW;
        float4 a0 = make_float4(0.f,0.f,0.f,0.f), b0 = a0, a1 = a0, b1 = a0;
        if (rowok && lo_ok) { a0 = *(const float4*)(s0 + (lane<<2));       a1 = *(const float4*)(s1 + (lane<<2)); }
        if (rowok && hi_ok) { b0 = *(const float4*)(s0 + 256 + (lane<<2)); b1 = *(const float4*)(s1 + 256 + (lane<<2)); }
        *(float4*)&xs[wv][0][0][lane<<2] = a0;
        *(float4*)&xs[wv][0][1][lane<<2] = a1;
        if (lane < 2) {
            *(float4*)&xs[wv][0][0][256 + (lane<<2)] = b0;
            *(float4*)&xs[wv][0][1][256 + (lane<<2)] = b1;
        }
    }

    // CRITICAL: compiler auto-unrolls trip-count-9 loops, then hoists all 81
    // filter loads -> 256 VGPR + scratch spill. unroll(disable) is the fix.
    #pragma clang loop unroll(disable)
    for (int i = 0; i < KK; ++i) {
        const int buf = i & 1;

        // 1) issue next-row x staging loads first (consumed last this iter)
        float4 a0 = make_float4(0.f,0.f,0.f,0.f), b0 = a0, a1 = a0, b1 = a0;
        if (i < KK - 1) {
            const int hh = h - 3 + i;
            const bool rowok = (unsigned)hh < (unsigned)HH;
            const float* s0 = xr0 + (size_t)hh * WW;
            const float* s1 = xr1 + (size_t)hh * WW;
            if (rowok && lo_ok) { a0 = *(const float4*)(s0 + (lane<<2));       a1 = *(const float4*)(s1 + (lane<<2)); }
            if (rowok && hi_ok) { b0 = *(const float4*)(s0 + 256 + (lane<<2)); b1 = *(const float4*)(s1 + 256 + (lane<<2)); }
        }

        // 2) filter taps for row i: 9 coalesced float4 loads (4 px per lane)
        float4 f[9];
        {
            const float* fi = fptr + (size_t)i * KK * HW;
            #pragma unroll
            for (int j = 0; j < 9; ++j) f[j] = *(const float4*)(fi + (size_t)j * HW);
        }

        // 3) x window from wave-private LDS: 12 floats per channel
        float v0[12], v1[12];
        {
            const float* p0 = &xs[wv][buf][0][lane << 2];
            const float* p1 = &xs[wv][buf][1][lane << 2];
            float4 u;
            u = *(const float4*)(p0 + 0); v0[0]=u.x; v0[1]=u.y; v0[2] =u.z; v0[3] =u.w;
            u = *(const float4*)(p0 + 4); v0[4]=u.x; v0[5]=u.y; v0[6] =u.z; v0[7] =u.w;
            u = *(const float4*)(p0 + 8); v0[8]=u.x; v0[9]=u.y; v0[10]=u.z; v0[11]=u.w;
            u = *(const float4*)(p1 + 0); v1[0]=u.x; v1[1]=u.y; v1[2] =u.z; v1[3] =u.w;
            u = *(const float4*)(p1 + 4); v1[4]=u.x; v1[5]=u.y; v1[6] =u.z; v1[7] =u.w;
            u = *(const float4*)(p1 + 8); v1[8]=u.x; v1[9]=u.y; v1[10]=u.z; v1[11]=u.w;
        }

        // 4) 72 FMAs (2 ch x 4 px x 9 taps)
        #pragma unroll
        for (int j = 0; j < 9; ++j) {
            acc0[0] = fmaf(f[j].x, v0[j+0], acc0[0]);
            acc0[1] = fmaf(f[j].y, v0[j+1], acc0[1]);
            acc0[2] = fmaf(f[j].z, v0[j+2], acc0[2]);
            acc0[3] = fmaf(f[j].w, v0[j+3], acc0[3]);
            acc1[0] = fmaf(f[j].x, v1[j+0], acc1[0]);
            acc1[1] = fmaf(f[j].y, v1[j+1], acc1[1]);
            acc1[2] = fmaf(f[j].z, v1[j+2], acc1[2]);
            acc1[3] = fmaf(f[j].w, v1[j+3], acc1[3]);
        }

        // 5) store staged row into the other wave-private buffer
        if (i < KK - 1) {
            *(float4*)&xs[wv][buf ^ 1][0][lane<<2] = a0;
            *(float4*)&xs[wv][buf ^ 1][1][lane<<2] = a1;
            if (lane < 2) {
                *(float4*)&xs[wv][buf ^ 1][0][256 + (lane<<2)] = b0;
                *(float4*)&xs[wv][buf ^ 1][1][256 + (lane<<2)] = b1;
            }
        }
    }

    {
        const float4 o0 = make_float4(acc0[0], acc0[1], acc0[2], acc0[3]);
        const float4 o1 = make_float4(acc1[0], acc1[1], acc1[2], acc1[3]);
        *(float4*)(out + ((size_t)(n * CC + c0)     * HH + h) * WW + w0) = o0;
        *(float4*)(out + ((size_t)(n * CC + c0 + 1) * HH + h) * WW + w0) = o1;
    }
}

extern "C" void kernel_launch(void* const* d_in, const int* in_sizes, int n_in,
                              void* d_out, int out_size, void* d_ws, size_t ws_size,
                              hipStream_t stream) {
    const float* x  = (const float*)d_in[0];
    const float* f  = (const float*)d_in[1];
    const float* fb = (const float*)d_in[2];
    float* o = (float*)d_out;
    hipLaunchKernelGGL(dynfilter_kernel, dim3(1024), dim3(256), 0, stream,
                       x, f, fb, o);
}

// Round 3
// 136.994 us; speedup vs baseline: 1.0347x; 1.0040x over previous
//
#include <hip/hip_runtime.h>

#define CC 8
#define HH 256
#define WW 512
#define KK 9
#define XF 272   // LDS floats per (wave,buf,ch) row: 264 used, padded to 16B multiple

__global__ __launch_bounds__(256, 4) void dynfilter_kernel(
    const float* __restrict__ x,
    const float* __restrict__ filt,
    const float* __restrict__ fbias,
    float* __restrict__ out)
{
    // Wave-private LDS double buffer: NO __syncthreads in this kernel.
    __shared__ __align__(16) float xs[4][2][2][XF];

    const int tid  = threadIdx.x;
    const int wv   = tid >> 6;          // wave -> channels {2wv, 2wv+1}
    const int lane = tid & 63;

    // XCD-aware bijective swizzle (nwg=1024, 8 XCDs, 128 blocks each).
    // HW round-robins blockIdx%8 across XCDs; remap so each XCD gets a
    // CONTIGUOUS work band (one n, 64-h band, both segs) -> its x rows are
    // fetched into its private L2 once instead of 4x across XCDs.
    const int bid0 = blockIdx.x;
    const int bid  = ((bid0 & 7) << 7) | (bid0 >> 3);   // (bid0%8)*128 + bid0/8

    const int seg = bid & 1;
    const int h   = (bid >> 1) & 255;
    const int n   = bid >> 9;

    const int w0      = seg * 256 + (lane << 2);  // 4 px per lane
    const int wstage0 = seg * 256 - 4;

    const size_t HW = (size_t)HH * WW;
    const int c0 = wv << 1;

    const float* xr0  = x + (size_t)(n * CC + c0)     * HW + wstage0;
    const float* xr1  = x + (size_t)(n * CC + c0 + 1) * HW + wstage0;
    const float* fptr = filt + ((size_t)(n * 81) * HH + h) * WW + w0;

    float acc0[4], acc1[4];
    {
        const float4 b4 = *(const float4*)(fbias + ((size_t)(n * HH + h)) * WW + w0);
        acc0[0]=b4.x; acc0[1]=b4.y; acc0[2]=b4.z; acc0[3]=b4.w;
        acc1[0]=b4.x; acc1[1]=b4.y; acc1[2]=b4.z; acc1[3]=b4.w;
    }

    const int wlo = wstage0 + (lane << 2);         // main float4 start coord
    const int whi = wstage0 + 256 + (lane << 2);   // tail float4 (lanes 0,1)
    const bool lo_ok = (unsigned)wlo < (unsigned)WW;
    const bool hi_ok = (lane < 2) && ((unsigned)whi < (unsigned)WW);

    // ---- prologue: stage row h-4 into buf 0 (wave-private, no barrier) ----
    {
        const int hh = h - 4;
        const bool rowok = hh >= 0;
        const float* s0 = xr0 + (size_t)hh * WW;
        const float* s1 = xr1 + (size_t)hh * WW;
        float4 a0 = make_float4(0.f,0.f,0.f,0.f), b0 = a0, a1 = a0, b1 = a0;
        if (rowok && lo_ok) { a0 = *(const float4*)(s0 + (lane<<2));       a1 = *(const float4*)(s1 + (lane<<2)); }
        if (rowok && hi_ok) { b0 = *(const float4*)(s0 + 256 + (lane<<2)); b1 = *(const float4*)(s1 + 256 + (lane<<2)); }
        *(float4*)&xs[wv][0][0][lane<<2] = a0;
        *(float4*)&xs[wv][0][1][lane<<2] = a1;
        if (lane < 2) {
            *(float4*)&xs[wv][0][0][256 + (lane<<2)] = b0;
            *(float4*)&xs[wv][0][1][256 + (lane<<2)] = b1;
        }
    }

    // CRITICAL: compiler auto-unrolls trip-count-9 loops, then hoists all 81
    // filter loads -> 256 VGPR + scratch spill. unroll(disable) is the fix.
    #pragma clang loop unroll(disable)
    for (int i = 0; i < KK; ++i) {
        const int buf = i & 1;

        // 1) issue next-row x staging loads first (consumed last this iter)
        float4 a0 = make_float4(0.f,0.f,0.f,0.f), b0 = a0, a1 = a0, b1 = a0;
        if (i < KK - 1) {
            const int hh = h - 3 + i;
            const bool rowok = (unsigned)hh < (unsigned)HH;
            const float* s0 = xr0 + (size_t)hh * WW;
            const float* s1 = xr1 + (size_t)hh * WW;
            if (rowok && lo_ok) { a0 = *(const float4*)(s0 + (lane<<2));       a1 = *(const float4*)(s1 + (lane<<2)); }
            if (rowok && hi_ok) { b0 = *(const float4*)(s0 + 256 + (lane<<2)); b1 = *(const float4*)(s1 + 256 + (lane<<2)); }
        }

        // 2) filter taps for row i: 9 coalesced float4 loads (4 px per lane)
        float4 f[9];
        {
            const float* fi = fptr + (size_t)i * KK * HW;
            #pragma unroll
            for (int j = 0; j < 9; ++j) f[j] = *(const float4*)(fi + (size_t)j * HW);
        }

        // 3) x window from wave-private LDS: 12 floats per channel
        float v0[12], v1[12];
        {
            const float* p0 = &xs[wv][buf][0][lane << 2];
            const float* p1 = &xs[wv][buf][1][lane << 2];
            float4 u;
            u = *(const float4*)(p0 + 0); v0[0]=u.x; v0[1]=u.y; v0[2] =u.z; v0[3] =u.w;
            u = *(const float4*)(p0 + 4); v0[4]=u.x; v0[5]=u.y; v0[6] =u.z; v0[7] =u.w;
            u = *(const float4*)(p0 + 8); v0[8]=u.x; v0[9]=u.y; v0[10]=u.z; v0[11]=u.w;
            u = *(const float4*)(p1 + 0); v1[0]=u.x; v1[1]=u.y; v1[2] =u.z; v1[3] =u.w;
            u = *(const float4*)(p1 + 4); v1[4]=u.x; v1[5]=u.y; v1[6] =u.z; v1[7] =u.w;
            u = *(const float4*)(p1 + 8); v1[8]=u.x; v1[9]=u.y; v1[10]=u.z; v1[11]=u.w;
        }

        // 4) 72 FMAs (2 ch x 4 px x 9 taps)
        #pragma unroll
        for (int j = 0; j < 9; ++j) {
            acc0[0] = fmaf(f[j].x, v0[j+0], acc0[0]);
            acc0[1] = fmaf(f[j].y, v0[j+1], acc0[1]);
            acc0[2] = fmaf(f[j].z, v0[j+2], acc0[2]);
            acc0[3] = fmaf(f[j].w, v0[j+3], acc0[3]);
            acc1[0] = fmaf(f[j].x, v1[j+0], acc1[0]);
            acc1[1] = fmaf(f[j].y, v1[j+1], acc1[1]);
            acc1[2] = fmaf(f[j].z, v1[j+2], acc1[2]);
            acc1[3] = fmaf(f[j].w, v1[j+3], acc1[3]);
        }

        // 5) store staged row into the other wave-private buffer
        if (i < KK - 1) {
            *(float4*)&xs[wv][buf ^ 1][0][lane<<2] = a0;
            *(float4*)&xs[wv][buf ^ 1][1][lane<<2] = a1;
            if (lane < 2) {
                *(float4*)&xs[wv][buf ^ 1][0][256 + (lane<<2)] = b0;
                *(float4*)&xs[wv][buf ^ 1][1][256 + (lane<<2)] = b1;
            }
        }
    }

    {
        const float4 o0 = make_float4(acc0[0], acc0[1], acc0[2], acc0[3]);
        const float4 o1 = make_float4(acc1[0], acc1[1], acc1[2], acc1[3]);
        *(float4*)(out + ((size_t)(n * CC + c0)     * HH + h) * WW + w0) = o0;
        *(float4*)(out + ((size_t)(n * CC + c0 + 1) * HH + h) * WW + w0) = o1;
    }
}

extern "C" void kernel_launch(void* const* d_in, const int* in_sizes, int n_in,
                              void* d_out, int out_size, void* d_ws, size_t ws_size,
                              hipStream_t stream) {
    const float* x  = (const float*)d_in[0];
    const float* f  = (const float*)d_in[1];
    const float* fb = (const float*)d_in[2];
    float* o = (float*)d_out;
    hipLaunchKernelGGL(dynfilter_kernel, dim3(1024), dim3(256), 0, stream,
                       x, f, fb, o);
}